// Round 1
// baseline (1488.820 us; speedup 1.0000x reference)
//
#include <hip/hip_runtime.h>

// ---------------------------------------------------------------------------
// GCN 2-layer forward on MI355X.
//   deg[n] = 1 + #edges with dst==n ; dinv = rsqrt(deg)
//   L1: H1 = x@W1 ; AGG = b1 + H1*dinv^2 (self) + sum_e H1[src]*dinv[s]*dinv[d]
//   L2: H3 = relu(AGG)@W2 ; out = b2 + H3*dinv^2 + sum_e H3[src]*norm
// Aggregation for layer 2 done AFTER the matmul (40 ch instead of 128).
// ---------------------------------------------------------------------------

__global__ __launch_bounds__(256) void k_deg_init(float* __restrict__ deg, int n) {
    int i = blockIdx.x * 256 + threadIdx.x;
    if (i < n) deg[i] = 1.0f;   // self-loop
}

__global__ __launch_bounds__(256) void k_deg_count(const int* __restrict__ dst,
                                                   float* __restrict__ deg, int m) {
    int i = blockIdx.x * 256 + threadIdx.x;
    if (i < m) atomicAdd(&deg[dst[i]], 1.0f);
}

__global__ __launch_bounds__(256) void k_dinv(const float* __restrict__ deg,
                                              float* __restrict__ dinv, int n) {
    int i = blockIdx.x * 256 + threadIdx.x;
    if (i < n) dinv[i] = rsqrtf(deg[i]);
}

// GEMM1: [n,128] @ [128,128]; 64-row x 128-col tile per 256-thread block.
// Epilogue fuses the self-loop term + bias into AGG.
__global__ __launch_bounds__(256) void k_gemm1(
    const float* __restrict__ X, const float* __restrict__ W,
    const float* __restrict__ B, const float* __restrict__ dinv,
    float* __restrict__ H, float* __restrict__ AGG, int n)
{
    __shared__ float xs[64][36];    // KC=32 chunk, pad 36 keeps float4 stores aligned
    __shared__ float ws[32][128];
    const int t  = threadIdx.x;
    const int tx = t & 31;          // col group (4 cols)
    const int ty = t >> 5;          // row group (8 rows)
    const int r0 = blockIdx.x * 64;
    float acc[8][4] = {};

    for (int kc = 0; kc < 128; kc += 32) {
#pragma unroll
        for (int i = 0; i < 2; ++i) {
            int idx = t + i * 256;          // 0..511
            int row = idx >> 3;             // 64 rows
            int q   = idx & 7;              // 8 float4 per row-chunk
            int r   = r0 + row;
            float4 v = make_float4(0.f, 0.f, 0.f, 0.f);
            if (r < n) v = *(const float4*)&X[(size_t)r * 128 + kc + q * 4];
            *(float4*)&xs[row][q * 4] = v;
        }
#pragma unroll
        for (int i = 0; i < 4; ++i) {
            int idx = t + i * 256;          // 0..1023
            int kk  = idx >> 5;
            int cg  = idx & 31;
            *(float4*)&ws[kk][cg * 4] = *(const float4*)&W[(size_t)(kc + kk) * 128 + cg * 4];
        }
        __syncthreads();
#pragma unroll
        for (int kk = 0; kk < 32; ++kk) {
            float4 wv = *(const float4*)&ws[kk][tx * 4];
#pragma unroll
            for (int i = 0; i < 8; ++i) {
                float xv = xs[ty * 8 + i][kk];
                acc[i][0] = fmaf(xv, wv.x, acc[i][0]);
                acc[i][1] = fmaf(xv, wv.y, acc[i][1]);
                acc[i][2] = fmaf(xv, wv.z, acc[i][2]);
                acc[i][3] = fmaf(xv, wv.w, acc[i][3]);
            }
        }
        __syncthreads();
    }

    const float bv0 = B[tx * 4 + 0], bv1 = B[tx * 4 + 1];
    const float bv2 = B[tx * 4 + 2], bv3 = B[tx * 4 + 3];
#pragma unroll
    for (int i = 0; i < 8; ++i) {
        int r = r0 + ty * 8 + i;
        if (r < n) {
            float di = dinv[r], d2 = di * di;
            float4 h = make_float4(acc[i][0], acc[i][1], acc[i][2], acc[i][3]);
            *(float4*)&H[(size_t)r * 128 + tx * 4] = h;
            float4 a = make_float4(fmaf(h.x, d2, bv0), fmaf(h.y, d2, bv1),
                                   fmaf(h.z, d2, bv2), fmaf(h.w, d2, bv3));
            *(float4*)&AGG[(size_t)r * 128 + tx * 4] = a;
        }
    }
}

// edge scatter, layer 1: 32 threads/edge, float4 each, 4 scalar atomics
__global__ __launch_bounds__(256) void k_edge1(
    const int* __restrict__ src, const int* __restrict__ dst,
    const float* __restrict__ dinv, const float* __restrict__ H,
    float* __restrict__ AGG, int m)
{
    int w = blockIdx.x * 256 + threadIdx.x;
    int e = w >> 5, l = w & 31;
    if (e >= m) return;
    int s = src[e], d = dst[e];
    float nrm = dinv[s] * dinv[d];
    float4 v = *(const float4*)&H[(size_t)s * 128 + l * 4];
    float* p = &AGG[(size_t)d * 128 + l * 4];
    atomicAdd(p + 0, v.x * nrm);
    atomicAdd(p + 1, v.y * nrm);
    atomicAdd(p + 2, v.z * nrm);
    atomicAdd(p + 3, v.w * nrm);
}

// GEMM2: relu(AGG)[n,128] @ [128,40]; 128-row tile per 256-thread block.
// Epilogue fuses self-loop + bias into OUT (full init of d_out).
__global__ __launch_bounds__(256) void k_gemm2(
    const float* __restrict__ X, const float* __restrict__ W,
    const float* __restrict__ B, const float* __restrict__ dinv,
    float* __restrict__ H3, float* __restrict__ OUT, int n)
{
    __shared__ float xs[128][17];     // KC=16 chunk, pad 17 -> conflict-free reads
    __shared__ float ws[128 * 40];    // full W2, 20 KB
    const int t  = threadIdx.x;
    const int tx = t & 7;             // 8 col groups (5 cols each)
    const int ty = t >> 3;            // 32 row groups (4 rows each)
    const int r0 = blockIdx.x * 128;

#pragma unroll
    for (int i = 0; i < 20; ++i) ws[t + i * 256] = W[t + i * 256];

    float acc[4][5] = {};
    for (int kc = 0; kc < 128; kc += 16) {
#pragma unroll
        for (int i = 0; i < 2; ++i) {
            int idx = t + i * 256;        // 0..511
            int row = idx >> 2;           // 128 rows
            int q   = idx & 3;            // 4 float4 per row-chunk
            int r   = r0 + row;
            float4 v = make_float4(0.f, 0.f, 0.f, 0.f);
            if (r < n) v = *(const float4*)&X[(size_t)r * 128 + kc + q * 4];
            float* p = &xs[row][q * 4];
            p[0] = fmaxf(v.x, 0.f);
            p[1] = fmaxf(v.y, 0.f);
            p[2] = fmaxf(v.z, 0.f);
            p[3] = fmaxf(v.w, 0.f);
        }
        __syncthreads();
#pragma unroll
        for (int kk = 0; kk < 16; ++kk) {
            float wv[5];
            const float* wp = &ws[(kc + kk) * 40 + tx * 5];
#pragma unroll
            for (int j = 0; j < 5; ++j) wv[j] = wp[j];
#pragma unroll
            for (int i = 0; i < 4; ++i) {
                float xv = xs[ty * 4 + i][kk];
#pragma unroll
                for (int j = 0; j < 5; ++j) acc[i][j] = fmaf(xv, wv[j], acc[i][j]);
            }
        }
        __syncthreads();
    }

#pragma unroll
    for (int i = 0; i < 4; ++i) {
        int r = r0 + ty * 4 + i;
        if (r < n) {
            float di = dinv[r], d2 = di * di;
#pragma unroll
            for (int j = 0; j < 5; ++j) {
                int c = tx * 5 + j;
                float h = acc[i][j];
                H3[(size_t)r * 40 + c]  = h;
                OUT[(size_t)r * 40 + c] = fmaf(h, d2, B[c]);
            }
        }
    }
}

// edge scatter, layer 2: 10 threads/edge (40 ch), float4 each
__global__ __launch_bounds__(256) void k_edge2(
    const int* __restrict__ src, const int* __restrict__ dst,
    const float* __restrict__ dinv, const float* __restrict__ H3,
    float* __restrict__ OUT, int m)
{
    unsigned w = blockIdx.x * 256u + threadIdx.x;
    unsigned e = w / 10u;
    unsigned q = w - e * 10u;
    if (e >= (unsigned)m) return;
    int s = src[e], d = dst[e];
    float nrm = dinv[s] * dinv[d];
    float4 v = *(const float4*)&H3[(size_t)s * 40 + q * 4];
    float* p = &OUT[(size_t)d * 40 + q * 4];
    atomicAdd(p + 0, v.x * nrm);
    atomicAdd(p + 1, v.y * nrm);
    atomicAdd(p + 2, v.z * nrm);
    atomicAdd(p + 3, v.w * nrm);
}

extern "C" void kernel_launch(void* const* d_in, const int* in_sizes, int n_in,
                              void* d_out, int out_size, void* d_ws, size_t ws_size,
                              hipStream_t stream) {
    const float* x  = (const float*)d_in[0];
    const int*   ei = (const int*)d_in[1];
    const float* W1 = (const float*)d_in[2];
    const float* b1 = (const float*)d_in[3];
    const float* W2 = (const float*)d_in[4];
    const float* b2 = (const float*)d_in[5];
    float* out = (float*)d_out;

    const int n = in_sizes[0] / 128;     // 50000
    const int m = in_sizes[1] / 2;       // 600000
    const int* src = ei;
    const int* dst = ei + m;

    char* wsb = (char*)d_ws;
    float* deg  = (float*)wsb;
    float* dinv = deg + n;
    size_t off = ((size_t)2 * n * sizeof(float) + 255) & ~(size_t)255;
    float* H1  = (float*)(wsb + off);        // [n,128]
    float* AGG = H1 + (size_t)n * 128;       // [n,128]
    float* H3  = H1;                         // alias: H1 dead after edge1

    k_deg_init <<<(n + 255) / 256, 256, 0, stream>>>(deg, n);
    k_deg_count<<<(m + 255) / 256, 256, 0, stream>>>(dst, deg, m);
    k_dinv     <<<(n + 255) / 256, 256, 0, stream>>>(deg, dinv, n);

    k_gemm1<<<(n + 63) / 64, 256, 0, stream>>>(x, W1, b1, dinv, H1, AGG, n);

    {
        long long items = (long long)m * 32;
        k_edge1<<<(int)((items + 255) / 256), 256, 0, stream>>>(src, dst, dinv, H1, AGG, m);
    }

    k_gemm2<<<(n + 127) / 128, 256, 0, stream>>>(AGG, W2, b2, dinv, H3, out, n);

    {
        long long items = (long long)m * 10;
        k_edge2<<<(int)((items + 255) / 256), 256, 0, stream>>>(src, dst, dinv, H3, out, m);
    }
}

// Round 2
// 213.853 us; speedup vs baseline: 6.9619x; 6.9619x over previous
//
#include <hip/hip_runtime.h>

// ---------------------------------------------------------------------------
// GCN 2-layer forward, CSR-gather formulation (no fp32 scatter atomics).
//   1. cnt[d] = #edges into d (int atomics); dinv = rsqrt(cnt+1)
//   2. rowstart = exclusive_scan(cnt); scatter (src, norm) per edge into CSR
//   3. H1 = x@W1
//   4. AGG = b1 + H1*dinv^2 + sum_{j in row} H1[esrc[j]] * enorm[j]   (gather)
//   5. H3 = relu(AGG)@W2
//   6. OUT = b2 + H3*dinv^2 + gather(H3)                              (gather)
// ---------------------------------------------------------------------------

__global__ __launch_bounds__(256) void k_zero(int* __restrict__ cnt, int n) {
    int i = blockIdx.x * 256 + threadIdx.x;
    if (i < n) cnt[i] = 0;
}

__global__ __launch_bounds__(256) void k_hist(const int* __restrict__ dst,
                                              int* __restrict__ cnt, int m) {
    int i = blockIdx.x * 256 + threadIdx.x;
    if (i < m) atomicAdd(&cnt[dst[i]], 1);
}

__global__ __launch_bounds__(256) void k_dinv(const int* __restrict__ cnt,
                                              float* __restrict__ dinv, int n) {
    int i = blockIdx.x * 256 + threadIdx.x;
    if (i < n) dinv[i] = rsqrtf((float)cnt[i] + 1.0f);
}

// block-local inclusive scan (Hillis-Steele), writes exclusive + block sums
__global__ __launch_bounds__(256) void k_scan_local(const int* __restrict__ cnt,
                                                    int* __restrict__ rowstart,
                                                    int* __restrict__ bsum, int n) {
    __shared__ int s[256];
    int t = threadIdx.x;
    int i = blockIdx.x * 256 + t;
    int v = (i < n) ? cnt[i] : 0;
    s[t] = v;
    __syncthreads();
#pragma unroll
    for (int off = 1; off < 256; off <<= 1) {
        int x = s[t];
        if (t >= off) x += s[t - off];
        __syncthreads();
        s[t] = x;
        __syncthreads();
    }
    if (i < n) rowstart[i] = s[t] - v;        // exclusive
    if (t == 255) bsum[blockIdx.x] = s[255];
}

__global__ __launch_bounds__(256) void k_scan_bsum(int* __restrict__ bsum,
                                                   int* __restrict__ boff, int nb) {
    __shared__ int s[256];
    int t = threadIdx.x;
    int v = (t < nb) ? bsum[t] : 0;
    s[t] = v;
    __syncthreads();
#pragma unroll
    for (int off = 1; off < 256; off <<= 1) {
        int x = s[t];
        if (t >= off) x += s[t - off];
        __syncthreads();
        s[t] = x;
        __syncthreads();
    }
    if (t < nb) boff[t] = s[t] - v;           // exclusive
}

__global__ __launch_bounds__(256) void k_scan_add(int* __restrict__ rowstart,
                                                  const int* __restrict__ boff,
                                                  int* __restrict__ cursor, int n, int m) {
    int i = blockIdx.x * 256 + threadIdx.x;
    if (i < n) {
        int v = rowstart[i] + boff[blockIdx.x];
        rowstart[i] = v;
        cursor[i]   = v;
    }
    if (i == 0) rowstart[n] = m;
}

__global__ __launch_bounds__(256) void k_scatter(const int* __restrict__ src,
                                                 const int* __restrict__ dst,
                                                 const float* __restrict__ dinv,
                                                 int* __restrict__ cursor,
                                                 int* __restrict__ esrc,
                                                 float* __restrict__ enorm, int m) {
    int e = blockIdx.x * 256 + threadIdx.x;
    if (e >= m) return;
    int s = src[e], d = dst[e];
    int pos = atomicAdd(&cursor[d], 1);
    esrc[pos]  = s;
    enorm[pos] = dinv[s] * dinv[d];
}

// GEMM1: [n,128] @ [128,128]; 64-row x 128-col tile per 256-thread block.
__global__ __launch_bounds__(256) void k_gemm1(
    const float* __restrict__ X, const float* __restrict__ W,
    float* __restrict__ H, int n)
{
    __shared__ float xs[64][36];
    __shared__ float ws[32][128];
    const int t  = threadIdx.x;
    const int tx = t & 31;
    const int ty = t >> 5;
    const int r0 = blockIdx.x * 64;
    float acc[8][4] = {};

    for (int kc = 0; kc < 128; kc += 32) {
#pragma unroll
        for (int i = 0; i < 2; ++i) {
            int idx = t + i * 256;
            int row = idx >> 3;
            int q   = idx & 7;
            int r   = r0 + row;
            float4 v = make_float4(0.f, 0.f, 0.f, 0.f);
            if (r < n) v = *(const float4*)&X[(size_t)r * 128 + kc + q * 4];
            *(float4*)&xs[row][q * 4] = v;
        }
#pragma unroll
        for (int i = 0; i < 4; ++i) {
            int idx = t + i * 256;
            int kk  = idx >> 5;
            int cg  = idx & 31;
            *(float4*)&ws[kk][cg * 4] = *(const float4*)&W[(size_t)(kc + kk) * 128 + cg * 4];
        }
        __syncthreads();
#pragma unroll
        for (int kk = 0; kk < 32; ++kk) {
            float4 wv = *(const float4*)&ws[kk][tx * 4];
#pragma unroll
            for (int i = 0; i < 8; ++i) {
                float xv = xs[ty * 8 + i][kk];
                acc[i][0] = fmaf(xv, wv.x, acc[i][0]);
                acc[i][1] = fmaf(xv, wv.y, acc[i][1]);
                acc[i][2] = fmaf(xv, wv.z, acc[i][2]);
                acc[i][3] = fmaf(xv, wv.w, acc[i][3]);
            }
        }
        __syncthreads();
    }

#pragma unroll
    for (int i = 0; i < 8; ++i) {
        int r = r0 + ty * 8 + i;
        if (r < n)
            *(float4*)&H[(size_t)r * 128 + tx * 4] =
                make_float4(acc[i][0], acc[i][1], acc[i][2], acc[i][3]);
    }
}

// layer-1 aggregation: 32 lanes/row (float4 each), gather over CSR row
__global__ __launch_bounds__(256) void k_agg1(
    const int* __restrict__ rowstart, const int* __restrict__ esrc,
    const float* __restrict__ enorm, const float* __restrict__ H1,
    const float* __restrict__ B, const float* __restrict__ dinv,
    float* __restrict__ AGG, int n)
{
    int t = threadIdx.x;
    int lane = t & 31;
    int r = blockIdx.x * 8 + (t >> 5);
    if (r >= n) return;
    float di = dinv[r], d2 = di * di;
    float4 h  = *(const float4*)&H1[(size_t)r * 128 + lane * 4];
    float4 bv = *(const float4*)&B[lane * 4];
    float4 acc = make_float4(fmaf(h.x, d2, bv.x), fmaf(h.y, d2, bv.y),
                             fmaf(h.z, d2, bv.z), fmaf(h.w, d2, bv.w));
    int j1 = rowstart[r + 1];
    for (int j = rowstart[r]; j < j1; ++j) {
        int   s = esrc[j];
        float w = enorm[j];
        float4 v = *(const float4*)&H1[(size_t)s * 128 + lane * 4];
        acc.x = fmaf(v.x, w, acc.x);
        acc.y = fmaf(v.y, w, acc.y);
        acc.z = fmaf(v.z, w, acc.z);
        acc.w = fmaf(v.w, w, acc.w);
    }
    *(float4*)&AGG[(size_t)r * 128 + lane * 4] = acc;
}

// GEMM2: relu(AGG)[n,128] @ [128,40] -> H3
__global__ __launch_bounds__(256) void k_gemm2(
    const float* __restrict__ X, const float* __restrict__ W,
    float* __restrict__ H3, int n)
{
    __shared__ float xs[128][17];
    __shared__ float ws[128 * 40];
    const int t  = threadIdx.x;
    const int tx = t & 7;
    const int ty = t >> 3;
    const int r0 = blockIdx.x * 128;

#pragma unroll
    for (int i = 0; i < 20; ++i) ws[t + i * 256] = W[t + i * 256];

    float acc[4][5] = {};
    for (int kc = 0; kc < 128; kc += 16) {
#pragma unroll
        for (int i = 0; i < 2; ++i) {
            int idx = t + i * 256;
            int row = idx >> 2;
            int q   = idx & 3;
            int r   = r0 + row;
            float4 v = make_float4(0.f, 0.f, 0.f, 0.f);
            if (r < n) v = *(const float4*)&X[(size_t)r * 128 + kc + q * 4];
            float* p = &xs[row][q * 4];
            p[0] = fmaxf(v.x, 0.f);
            p[1] = fmaxf(v.y, 0.f);
            p[2] = fmaxf(v.z, 0.f);
            p[3] = fmaxf(v.w, 0.f);
        }
        __syncthreads();
#pragma unroll
        for (int kk = 0; kk < 16; ++kk) {
            float wv[5];
            const float* wp = &ws[(kc + kk) * 40 + tx * 5];
#pragma unroll
            for (int j = 0; j < 5; ++j) wv[j] = wp[j];
#pragma unroll
            for (int i = 0; i < 4; ++i) {
                float xv = xs[ty * 4 + i][kk];
#pragma unroll
                for (int j = 0; j < 5; ++j) acc[i][j] = fmaf(xv, wv[j], acc[i][j]);
            }
        }
        __syncthreads();
    }

#pragma unroll
    for (int i = 0; i < 4; ++i) {
        int r = r0 + ty * 4 + i;
        if (r < n) {
#pragma unroll
            for (int j = 0; j < 5; ++j)
                H3[(size_t)r * 40 + tx * 5 + j] = acc[i][j];
        }
    }
}

// layer-2 aggregation: 10 lanes/row (float4 each), 320-thread blocks (32 rows)
__global__ __launch_bounds__(320) void k_agg2(
    const int* __restrict__ rowstart, const int* __restrict__ esrc,
    const float* __restrict__ enorm, const float* __restrict__ H3,
    const float* __restrict__ B, const float* __restrict__ dinv,
    float* __restrict__ OUT, int n)
{
    int t = threadIdx.x;
    int r = blockIdx.x * 32 + t / 10;
    int q = t % 10;
    if (r >= n) return;
    float di = dinv[r], d2 = di * di;
    float4 h  = *(const float4*)&H3[(size_t)r * 40 + q * 4];
    float4 bv = *(const float4*)&B[q * 4];
    float4 acc = make_float4(fmaf(h.x, d2, bv.x), fmaf(h.y, d2, bv.y),
                             fmaf(h.z, d2, bv.z), fmaf(h.w, d2, bv.w));
    int j1 = rowstart[r + 1];
    for (int j = rowstart[r]; j < j1; ++j) {
        int   s = esrc[j];
        float w = enorm[j];
        float4 v = *(const float4*)&H3[(size_t)s * 40 + q * 4];
        acc.x = fmaf(v.x, w, acc.x);
        acc.y = fmaf(v.y, w, acc.y);
        acc.z = fmaf(v.z, w, acc.z);
        acc.w = fmaf(v.w, w, acc.w);
    }
    *(float4*)&OUT[(size_t)r * 40 + q * 4] = acc;
}

extern "C" void kernel_launch(void* const* d_in, const int* in_sizes, int n_in,
                              void* d_out, int out_size, void* d_ws, size_t ws_size,
                              hipStream_t stream) {
    const float* x  = (const float*)d_in[0];
    const int*   ei = (const int*)d_in[1];
    const float* W1 = (const float*)d_in[2];
    const float* b1 = (const float*)d_in[3];
    const float* W2 = (const float*)d_in[4];
    const float* b2 = (const float*)d_in[5];
    float* out = (float*)d_out;

    const int n = in_sizes[0] / 128;     // 50000
    const int m = in_sizes[1] / 2;       // 600000
    const int* src = ei;
    const int* dst = ei + m;
    const int nb = (n + 255) / 256;      // 196 scan blocks

    char* p = (char*)d_ws;
    auto take = [&](size_t bytes) { char* q = p; p += (bytes + 255) & ~(size_t)255; return q; };
    int*   cnt      = (int*)take(sizeof(int) * n);
    int*   rowstart = (int*)take(sizeof(int) * (n + 1));
    int*   cursor   = (int*)take(sizeof(int) * n);
    int*   bsum     = (int*)take(sizeof(int) * 256);
    int*   boff     = (int*)take(sizeof(int) * 256);
    int*   esrc     = (int*)take(sizeof(int) * m);
    float* enorm    = (float*)take(sizeof(float) * m);
    float* dinv     = (float*)take(sizeof(float) * n);
    float* H1       = (float*)take(sizeof(float) * (size_t)n * 128);
    float* AGG      = (float*)take(sizeof(float) * (size_t)n * 128);
    float* H3       = H1;                // H1 dead after k_agg1

    k_zero      <<<nb, 256, 0, stream>>>(cnt, n);
    k_hist      <<<(m + 255) / 256, 256, 0, stream>>>(dst, cnt, m);
    k_dinv      <<<nb, 256, 0, stream>>>(cnt, dinv, n);
    k_scan_local<<<nb, 256, 0, stream>>>(cnt, rowstart, bsum, n);
    k_scan_bsum <<<1, 256, 0, stream>>>(bsum, boff, nb);
    k_scan_add  <<<nb, 256, 0, stream>>>(rowstart, boff, cursor, n, m);
    k_scatter   <<<(m + 255) / 256, 256, 0, stream>>>(src, dst, dinv, cursor, esrc, enorm, m);

    k_gemm1<<<(n + 63) / 64, 256, 0, stream>>>(x, W1, H1, n);
    k_agg1 <<<(n + 7) / 8, 256, 0, stream>>>(rowstart, esrc, enorm, H1, b1, dinv, AGG, n);
    k_gemm2<<<(n + 127) / 128, 256, 0, stream>>>(AGG, W2, H3, n);
    k_agg2 <<<(n + 31) / 32, 320, 0, stream>>>(rowstart, esrc, enorm, H3, b2, dinv, out, n);
}

// Round 3
// 190.849 us; speedup vs baseline: 7.8010x; 1.1205x over previous
//
#include <hip/hip_runtime.h>

// ---------------------------------------------------------------------------
// GCN 2-layer forward, CSR-gather formulation.
//   cnt/scan/scatter build CSR of (src,norm) int2 pairs sorted by dst.
//   H1 = x@W1
//   AGG = relu(b1 + H1*dinv^2 + sum_row H1[src]*norm)    (4-way unrolled gather)
//   H3 = AGG@W2
//   OUT = b2 + H3*dinv^2 + sum_row H3[src]*norm          (4-way unrolled gather)
// ---------------------------------------------------------------------------

__global__ __launch_bounds__(256) void k_hist(const int* __restrict__ dst,
                                              int* __restrict__ cnt, int m) {
    int i = blockIdx.x * 256 + threadIdx.x;
    if (i < m) atomicAdd(&cnt[dst[i]], 1);
}

// block-local scan + dinv fused
__global__ __launch_bounds__(256) void k_scan_local(const int* __restrict__ cnt,
                                                    int* __restrict__ rowstart,
                                                    int* __restrict__ bsum,
                                                    float* __restrict__ dinv, int n) {
    __shared__ int s[256];
    int t = threadIdx.x;
    int i = blockIdx.x * 256 + t;
    int v = (i < n) ? cnt[i] : 0;
    if (i < n) dinv[i] = rsqrtf((float)v + 1.0f);
    s[t] = v;
    __syncthreads();
#pragma unroll
    for (int off = 1; off < 256; off <<= 1) {
        int x = s[t];
        if (t >= off) x += s[t - off];
        __syncthreads();
        s[t] = x;
        __syncthreads();
    }
    if (i < n) rowstart[i] = s[t] - v;        // exclusive
    if (t == 255) bsum[blockIdx.x] = s[255];
}

__global__ __launch_bounds__(256) void k_scan_bsum(int* __restrict__ bsum,
                                                   int* __restrict__ boff, int nb) {
    __shared__ int s[256];
    int t = threadIdx.x;
    int v = (t < nb) ? bsum[t] : 0;
    s[t] = v;
    __syncthreads();
#pragma unroll
    for (int off = 1; off < 256; off <<= 1) {
        int x = s[t];
        if (t >= off) x += s[t - off];
        __syncthreads();
        s[t] = x;
        __syncthreads();
    }
    if (t < nb) boff[t] = s[t] - v;           // exclusive
}

__global__ __launch_bounds__(256) void k_scan_add(int* __restrict__ rowstart,
                                                  const int* __restrict__ boff,
                                                  int* __restrict__ cursor, int n, int m) {
    int i = blockIdx.x * 256 + threadIdx.x;
    if (i < n) {
        int v = rowstart[i] + boff[blockIdx.x];
        rowstart[i] = v;
        cursor[i]   = v;
    }
    if (i == 0) rowstart[n] = m;
}

__global__ __launch_bounds__(256) void k_scatter(const int* __restrict__ src,
                                                 const int* __restrict__ dst,
                                                 const float* __restrict__ dinv,
                                                 int* __restrict__ cursor,
                                                 int2* __restrict__ epair, int m) {
    int e = blockIdx.x * 256 + threadIdx.x;
    if (e >= m) return;
    int s = src[e], d = dst[e];
    int pos = atomicAdd(&cursor[d], 1);
    epair[pos] = make_int2(s, __float_as_int(dinv[s] * dinv[d]));
}

// GEMM1: [n,128] @ [128,128]; 128x128 tile, 8x8 micro-tile per thread.
// Rows assigned strided (ty + 16*i) -> xs reads hit 4 distinct banks/wave.
__global__ __launch_bounds__(256) void k_gemm1(
    const float* __restrict__ X, const float* __restrict__ W,
    float* __restrict__ H, int n)
{
    __shared__ float xs[128][36];
    __shared__ float ws[32][128];
    const int t  = threadIdx.x;
    const int tx = t & 15;          // 16 col groups (8 cols each)
    const int ty = t >> 4;          // 16 row slots; rows ty + 16*i
    const int r0 = blockIdx.x * 128;
    float acc[8][8] = {};

    for (int kc = 0; kc < 128; kc += 32) {
#pragma unroll
        for (int i = 0; i < 4; ++i) {
            int idx = t + i * 256;          // 0..1023
            int row = idx >> 3;             // 128 rows
            int q   = idx & 7;              // 8 float4 per row-chunk
            int r   = r0 + row;
            float4 v = make_float4(0.f, 0.f, 0.f, 0.f);
            if (r < n) v = *(const float4*)&X[(size_t)r * 128 + kc + q * 4];
            *(float4*)&xs[row][q * 4] = v;
        }
#pragma unroll
        for (int i = 0; i < 4; ++i) {
            int idx = t + i * 256;          // 0..1023
            int kk  = idx >> 5;
            int cg  = idx & 31;
            *(float4*)&ws[kk][cg * 4] = *(const float4*)&W[(size_t)(kc + kk) * 128 + cg * 4];
        }
        __syncthreads();
#pragma unroll
        for (int kk = 0; kk < 32; ++kk) {
            float xv[8];
#pragma unroll
            for (int i = 0; i < 8; ++i) xv[i] = xs[ty + 16 * i][kk];
            float4 w0 = *(const float4*)&ws[kk][tx * 8];
            float4 w1 = *(const float4*)&ws[kk][tx * 8 + 4];
#pragma unroll
            for (int i = 0; i < 8; ++i) {
                acc[i][0] = fmaf(xv[i], w0.x, acc[i][0]);
                acc[i][1] = fmaf(xv[i], w0.y, acc[i][1]);
                acc[i][2] = fmaf(xv[i], w0.z, acc[i][2]);
                acc[i][3] = fmaf(xv[i], w0.w, acc[i][3]);
                acc[i][4] = fmaf(xv[i], w1.x, acc[i][4]);
                acc[i][5] = fmaf(xv[i], w1.y, acc[i][5]);
                acc[i][6] = fmaf(xv[i], w1.z, acc[i][6]);
                acc[i][7] = fmaf(xv[i], w1.w, acc[i][7]);
            }
        }
        __syncthreads();
    }

#pragma unroll
    for (int i = 0; i < 8; ++i) {
        int r = r0 + ty + 16 * i;
        if (r < n) {
            *(float4*)&H[(size_t)r * 128 + tx * 8] =
                make_float4(acc[i][0], acc[i][1], acc[i][2], acc[i][3]);
            *(float4*)&H[(size_t)r * 128 + tx * 8 + 4] =
                make_float4(acc[i][4], acc[i][5], acc[i][6], acc[i][7]);
        }
    }
}

// layer-1 aggregation: 32 lanes/row (float4), 4-way unrolled gather, ReLU fused
__global__ __launch_bounds__(256) void k_agg1(
    const int* __restrict__ rowstart, const int2* __restrict__ epair,
    const float* __restrict__ H1, const float* __restrict__ B,
    const float* __restrict__ dinv, float* __restrict__ AGG, int n)
{
    int t = threadIdx.x;
    int lane = t & 31;
    int r = blockIdx.x * 8 + (t >> 5);
    if (r >= n) return;
    float di = dinv[r], d2 = di * di;
    float4 h  = *(const float4*)&H1[(size_t)r * 128 + lane * 4];
    float4 bv = *(const float4*)&B[lane * 4];
    float4 a0 = make_float4(fmaf(h.x, d2, bv.x), fmaf(h.y, d2, bv.y),
                            fmaf(h.z, d2, bv.z), fmaf(h.w, d2, bv.w));
    float4 a1 = make_float4(0.f, 0.f, 0.f, 0.f);
    float4 a2 = a1, a3 = a1;
    int j  = rowstart[r];
    int j1 = rowstart[r + 1];
    for (; j + 4 <= j1; j += 4) {
        int2 p0 = epair[j], p1 = epair[j + 1], p2 = epair[j + 2], p3 = epair[j + 3];
        float4 v0 = *(const float4*)&H1[(size_t)p0.x * 128 + lane * 4];
        float4 v1 = *(const float4*)&H1[(size_t)p1.x * 128 + lane * 4];
        float4 v2 = *(const float4*)&H1[(size_t)p2.x * 128 + lane * 4];
        float4 v3 = *(const float4*)&H1[(size_t)p3.x * 128 + lane * 4];
        float w0 = __int_as_float(p0.y), w1 = __int_as_float(p1.y);
        float w2 = __int_as_float(p2.y), w3 = __int_as_float(p3.y);
        a0.x = fmaf(v0.x, w0, a0.x); a0.y = fmaf(v0.y, w0, a0.y);
        a0.z = fmaf(v0.z, w0, a0.z); a0.w = fmaf(v0.w, w0, a0.w);
        a1.x = fmaf(v1.x, w1, a1.x); a1.y = fmaf(v1.y, w1, a1.y);
        a1.z = fmaf(v1.z, w1, a1.z); a1.w = fmaf(v1.w, w1, a1.w);
        a2.x = fmaf(v2.x, w2, a2.x); a2.y = fmaf(v2.y, w2, a2.y);
        a2.z = fmaf(v2.z, w2, a2.z); a2.w = fmaf(v2.w, w2, a2.w);
        a3.x = fmaf(v3.x, w3, a3.x); a3.y = fmaf(v3.y, w3, a3.y);
        a3.z = fmaf(v3.z, w3, a3.z); a3.w = fmaf(v3.w, w3, a3.w);
    }
    for (; j < j1; ++j) {
        int2 p = epair[j];
        float w = __int_as_float(p.y);
        float4 v = *(const float4*)&H1[(size_t)p.x * 128 + lane * 4];
        a0.x = fmaf(v.x, w, a0.x); a0.y = fmaf(v.y, w, a0.y);
        a0.z = fmaf(v.z, w, a0.z); a0.w = fmaf(v.w, w, a0.w);
    }
    float4 acc = make_float4(a0.x + a1.x + a2.x + a3.x,
                             a0.y + a1.y + a2.y + a3.y,
                             a0.z + a1.z + a2.z + a3.z,
                             a0.w + a1.w + a2.w + a3.w);
    acc.x = fmaxf(acc.x, 0.f);  acc.y = fmaxf(acc.y, 0.f);   // fused ReLU
    acc.z = fmaxf(acc.z, 0.f);  acc.w = fmaxf(acc.w, 0.f);
    *(float4*)&AGG[(size_t)r * 128 + lane * 4] = acc;
}

// GEMM2: AGG(already relu'd)[n,128] @ [128,40] -> H3
__global__ __launch_bounds__(256) void k_gemm2(
    const float* __restrict__ X, const float* __restrict__ W,
    float* __restrict__ H3, int n)
{
    __shared__ float xs[128][17];
    __shared__ float ws[128 * 40];
    const int t  = threadIdx.x;
    const int tx = t & 7;
    const int ty = t >> 3;
    const int r0 = blockIdx.x * 128;

#pragma unroll
    for (int i = 0; i < 20; ++i) ws[t + i * 256] = W[t + i * 256];

    float acc[4][5] = {};
    for (int kc = 0; kc < 128; kc += 16) {
#pragma unroll
        for (int i = 0; i < 2; ++i) {
            int idx = t + i * 256;
            int row = idx >> 2;
            int q   = idx & 3;
            int r   = r0 + row;
            float4 v = make_float4(0.f, 0.f, 0.f, 0.f);
            if (r < n) v = *(const float4*)&X[(size_t)r * 128 + kc + q * 4];
            *(float4*)&xs[row][q * 4] = v;   // note: [17] pad -> scalar stores ok
        }
        __syncthreads();
#pragma unroll
        for (int kk = 0; kk < 16; ++kk) {
            float wv[5];
            const float* wp = &ws[(kc + kk) * 40 + tx * 5];
#pragma unroll
            for (int j = 0; j < 5; ++j) wv[j] = wp[j];
#pragma unroll
            for (int i = 0; i < 4; ++i) {
                float xv = xs[ty * 4 + i][kk];
#pragma unroll
                for (int j = 0; j < 5; ++j) acc[i][j] = fmaf(xv, wv[j], acc[i][j]);
            }
        }
        __syncthreads();
    }

#pragma unroll
    for (int i = 0; i < 4; ++i) {
        int r = r0 + ty * 4 + i;
        if (r < n) {
#pragma unroll
            for (int j = 0; j < 5; ++j)
                H3[(size_t)r * 40 + tx * 5 + j] = acc[i][j];
        }
    }
}

// layer-2 aggregation: 10 lanes/row, 320-thread blocks, 4-way unrolled
__global__ __launch_bounds__(320) void k_agg2(
    const int* __restrict__ rowstart, const int2* __restrict__ epair,
    const float* __restrict__ H3, const float* __restrict__ B,
    const float* __restrict__ dinv, float* __restrict__ OUT, int n)
{
    int t = threadIdx.x;
    int r = blockIdx.x * 32 + t / 10;
    int q = t % 10;
    if (r >= n) return;
    float di = dinv[r], d2 = di * di;
    float4 h  = *(const float4*)&H3[(size_t)r * 40 + q * 4];
    float4 bv = *(const float4*)&B[q * 4];
    float4 a0 = make_float4(fmaf(h.x, d2, bv.x), fmaf(h.y, d2, bv.y),
                            fmaf(h.z, d2, bv.z), fmaf(h.w, d2, bv.w));
    float4 a1 = make_float4(0.f, 0.f, 0.f, 0.f);
    float4 a2 = a1, a3 = a1;
    int j  = rowstart[r];
    int j1 = rowstart[r + 1];
    for (; j + 4 <= j1; j += 4) {
        int2 p0 = epair[j], p1 = epair[j + 1], p2 = epair[j + 2], p3 = epair[j + 3];
        float4 v0 = *(const float4*)&H3[(size_t)p0.x * 40 + q * 4];
        float4 v1 = *(const float4*)&H3[(size_t)p1.x * 40 + q * 4];
        float4 v2 = *(const float4*)&H3[(size_t)p2.x * 40 + q * 4];
        float4 v3 = *(const float4*)&H3[(size_t)p3.x * 40 + q * 4];
        float w0 = __int_as_float(p0.y), w1 = __int_as_float(p1.y);
        float w2 = __int_as_float(p2.y), w3 = __int_as_float(p3.y);
        a0.x = fmaf(v0.x, w0, a0.x); a0.y = fmaf(v0.y, w0, a0.y);
        a0.z = fmaf(v0.z, w0, a0.z); a0.w = fmaf(v0.w, w0, a0.w);
        a1.x = fmaf(v1.x, w1, a1.x); a1.y = fmaf(v1.y, w1, a1.y);
        a1.z = fmaf(v1.z, w1, a1.z); a1.w = fmaf(v1.w, w1, a1.w);
        a2.x = fmaf(v2.x, w2, a2.x); a2.y = fmaf(v2.y, w2, a2.y);
        a2.z = fmaf(v2.z, w2, a2.z); a2.w = fmaf(v2.w, w2, a2.w);
        a3.x = fmaf(v3.x, w3, a3.x); a3.y = fmaf(v3.y, w3, a3.y);
        a3.z = fmaf(v3.z, w3, a3.z); a3.w = fmaf(v3.w, w3, a3.w);
    }
    for (; j < j1; ++j) {
        int2 p = epair[j];
        float w = __int_as_float(p.y);
        float4 v = *(const float4*)&H3[(size_t)p.x * 40 + q * 4];
        a0.x = fmaf(v.x, w, a0.x); a0.y = fmaf(v.y, w, a0.y);
        a0.z = fmaf(v.z, w, a0.z); a0.w = fmaf(v.w, w, a0.w);
    }
    float4 acc = make_float4(a0.x + a1.x + a2.x + a3.x,
                             a0.y + a1.y + a2.y + a3.y,
                             a0.z + a1.z + a2.z + a3.z,
                             a0.w + a1.w + a2.w + a3.w);
    *(float4*)&OUT[(size_t)r * 40 + q * 4] = acc;
}

extern "C" void kernel_launch(void* const* d_in, const int* in_sizes, int n_in,
                              void* d_out, int out_size, void* d_ws, size_t ws_size,
                              hipStream_t stream) {
    const float* x  = (const float*)d_in[0];
    const int*   ei = (const int*)d_in[1];
    const float* W1 = (const float*)d_in[2];
    const float* b1 = (const float*)d_in[3];
    const float* W2 = (const float*)d_in[4];
    const float* b2 = (const float*)d_in[5];
    float* out = (float*)d_out;

    const int n = in_sizes[0] / 128;     // 50000
    const int m = in_sizes[1] / 2;       // 600000
    const int* src = ei;
    const int* dst = ei + m;
    const int nb = (n + 255) / 256;      // 196 scan blocks

    char* p = (char*)d_ws;
    auto take = [&](size_t bytes) { char* q = p; p += (bytes + 255) & ~(size_t)255; return q; };
    int*   cnt      = (int*)take(sizeof(int) * n);
    int*   rowstart = (int*)take(sizeof(int) * (n + 1));
    int*   cursor   = (int*)take(sizeof(int) * n);
    int*   bsum     = (int*)take(sizeof(int) * 256);
    int*   boff     = (int*)take(sizeof(int) * 256);
    int2*  epair    = (int2*)take(sizeof(int2) * m);
    float* dinv     = (float*)take(sizeof(float) * n);
    float* H1       = (float*)take(sizeof(float) * (size_t)n * 128);
    float* AGG      = (float*)take(sizeof(float) * (size_t)n * 128);
    float* H3       = H1;                // H1 dead after k_agg1

    hipMemsetAsync(cnt, 0, sizeof(int) * n, stream);
    k_hist      <<<(m + 255) / 256, 256, 0, stream>>>(dst, cnt, m);
    k_scan_local<<<nb, 256, 0, stream>>>(cnt, rowstart, bsum, dinv, n);
    k_scan_bsum <<<1, 256, 0, stream>>>(bsum, boff, nb);
    k_scan_add  <<<nb, 256, 0, stream>>>(rowstart, boff, cursor, n, m);
    k_scatter   <<<(m + 255) / 256, 256, 0, stream>>>(src, dst, dinv, cursor, epair, m);

    k_gemm1<<<(n + 127) / 128, 256, 0, stream>>>(x, W1, H1, n);
    k_agg1 <<<(n + 7) / 8, 256, 0, stream>>>(rowstart, epair, H1, b1, dinv, AGG, n);
    k_gemm2<<<(n + 127) / 128, 256, 0, stream>>>(AGG, W2, H3, n);
    k_agg2 <<<(n + 31) / 32, 320, 0, stream>>>(rowstart, epair, H3, b2, dinv, out, n);
}

// Round 4
// 169.162 us; speedup vs baseline: 8.8011x; 1.1282x over previous
//
#include <hip/hip_runtime.h>

// ---------------------------------------------------------------------------
// GCN 2-layer forward, CSR-gather formulation, bf16 gather tables.
//   CSR build: hist -> scan -> scatter (src,norm) int2 pairs sorted by dst.
//   H1b = bf16(x@W1)                         [n,128] ushort
//   AGG = relu(b1 + H1b*dinv^2 + gather(H1b))  fp32 [n,128]
//   H3b = bf16(AGG@W2)                       [n,40] ushort
//   OUT = b2 + H3b*dinv^2 + gather(H3b)      fp32
// GEMM compute fp32; only aggregation operands rounded to bf16 (one RNE each).
// ---------------------------------------------------------------------------

__device__ inline unsigned short f2bf(float x) {
    unsigned u = __float_as_uint(x);
    unsigned r = (u + 0x7FFFu + ((u >> 16) & 1u)) >> 16;   // round-nearest-even
    return (unsigned short)r;
}
__device__ inline float bf2f(unsigned short b) {
    return __uint_as_float((unsigned)b << 16);
}

__global__ __launch_bounds__(256) void k_hist(const int* __restrict__ dst,
                                              int* __restrict__ cnt, int m) {
    int i = blockIdx.x * 256 + threadIdx.x;
    if (i < m) atomicAdd(&cnt[dst[i]], 1);
}

__global__ __launch_bounds__(256) void k_scan_local(const int* __restrict__ cnt,
                                                    int* __restrict__ rowstart,
                                                    int* __restrict__ bsum,
                                                    float* __restrict__ dinv, int n) {
    __shared__ int s[256];
    int t = threadIdx.x;
    int i = blockIdx.x * 256 + t;
    int v = (i < n) ? cnt[i] : 0;
    if (i < n) dinv[i] = rsqrtf((float)v + 1.0f);
    s[t] = v;
    __syncthreads();
#pragma unroll
    for (int off = 1; off < 256; off <<= 1) {
        int x = s[t];
        if (t >= off) x += s[t - off];
        __syncthreads();
        s[t] = x;
        __syncthreads();
    }
    if (i < n) rowstart[i] = s[t] - v;
    if (t == 255) bsum[blockIdx.x] = s[255];
}

__global__ __launch_bounds__(256) void k_scan_bsum(int* __restrict__ bsum,
                                                   int* __restrict__ boff, int nb) {
    __shared__ int s[256];
    int t = threadIdx.x;
    int v = (t < nb) ? bsum[t] : 0;
    s[t] = v;
    __syncthreads();
#pragma unroll
    for (int off = 1; off < 256; off <<= 1) {
        int x = s[t];
        if (t >= off) x += s[t - off];
        __syncthreads();
        s[t] = x;
        __syncthreads();
    }
    if (t < nb) boff[t] = s[t] - v;
}

__global__ __launch_bounds__(256) void k_scan_add(int* __restrict__ rowstart,
                                                  const int* __restrict__ boff,
                                                  int* __restrict__ cursor, int n, int m) {
    int i = blockIdx.x * 256 + threadIdx.x;
    if (i < n) {
        int v = rowstart[i] + boff[blockIdx.x];
        rowstart[i] = v;
        cursor[i]   = v;
    }
    if (i == 0) rowstart[n] = m;
}

__global__ __launch_bounds__(256) void k_scatter(const int* __restrict__ src,
                                                 const int* __restrict__ dst,
                                                 const float* __restrict__ dinv,
                                                 int* __restrict__ cursor,
                                                 int2* __restrict__ epair, int m) {
    int e = blockIdx.x * 256 + threadIdx.x;
    if (e >= m) return;
    int s = src[e], d = dst[e];
    int pos = atomicAdd(&cursor[d], 1);
    epair[pos] = make_int2(s, __float_as_int(dinv[s] * dinv[d]));
}

// GEMM1: [n,128] @ [128,128] fp32; 128x128 tile, 8x8 micro-tile; bf16 output.
__global__ __launch_bounds__(256) void k_gemm1(
    const float* __restrict__ X, const float* __restrict__ W,
    unsigned short* __restrict__ Hb, int n)
{
    __shared__ float xs[128][36];
    __shared__ float ws[32][128];
    const int t  = threadIdx.x;
    const int tx = t & 15;
    const int ty = t >> 4;
    const int r0 = blockIdx.x * 128;
    float acc[8][8] = {};

    for (int kc = 0; kc < 128; kc += 32) {
#pragma unroll
        for (int i = 0; i < 4; ++i) {
            int idx = t + i * 256;
            int row = idx >> 3;
            int q   = idx & 7;
            int r   = r0 + row;
            float4 v = make_float4(0.f, 0.f, 0.f, 0.f);
            if (r < n) v = *(const float4*)&X[(size_t)r * 128 + kc + q * 4];
            *(float4*)&xs[row][q * 4] = v;
        }
#pragma unroll
        for (int i = 0; i < 4; ++i) {
            int idx = t + i * 256;
            int kk  = idx >> 5;
            int cg  = idx & 31;
            *(float4*)&ws[kk][cg * 4] = *(const float4*)&W[(size_t)(kc + kk) * 128 + cg * 4];
        }
        __syncthreads();
#pragma unroll
        for (int kk = 0; kk < 32; ++kk) {
            float xv[8];
#pragma unroll
            for (int i = 0; i < 8; ++i) xv[i] = xs[ty + 16 * i][kk];
            float4 w0 = *(const float4*)&ws[kk][tx * 8];
            float4 w1 = *(const float4*)&ws[kk][tx * 8 + 4];
#pragma unroll
            for (int i = 0; i < 8; ++i) {
                acc[i][0] = fmaf(xv[i], w0.x, acc[i][0]);
                acc[i][1] = fmaf(xv[i], w0.y, acc[i][1]);
                acc[i][2] = fmaf(xv[i], w0.z, acc[i][2]);
                acc[i][3] = fmaf(xv[i], w0.w, acc[i][3]);
                acc[i][4] = fmaf(xv[i], w1.x, acc[i][4]);
                acc[i][5] = fmaf(xv[i], w1.y, acc[i][5]);
                acc[i][6] = fmaf(xv[i], w1.z, acc[i][6]);
                acc[i][7] = fmaf(xv[i], w1.w, acc[i][7]);
            }
        }
        __syncthreads();
    }

#pragma unroll
    for (int i = 0; i < 8; ++i) {
        int r = r0 + ty + 16 * i;
        if (r < n) {
            ushort4 o0 = make_ushort4(f2bf(acc[i][0]), f2bf(acc[i][1]),
                                      f2bf(acc[i][2]), f2bf(acc[i][3]));
            ushort4 o1 = make_ushort4(f2bf(acc[i][4]), f2bf(acc[i][5]),
                                      f2bf(acc[i][6]), f2bf(acc[i][7]));
            *(ushort4*)&Hb[(size_t)r * 128 + tx * 8]     = o0;
            *(ushort4*)&Hb[(size_t)r * 128 + tx * 8 + 4] = o1;
        }
    }
}

// layer-1 aggregation: 32 lanes/row (4 ch each, ushort4=8B), 4-way unrolled, ReLU
__global__ __launch_bounds__(256) void k_agg1(
    const int* __restrict__ rowstart, const int2* __restrict__ epair,
    const unsigned short* __restrict__ Hb, const float* __restrict__ B,
    const float* __restrict__ dinv, float* __restrict__ AGG, int n)
{
    int t = threadIdx.x;
    int lane = t & 31;
    int r = blockIdx.x * 8 + (t >> 5);
    if (r >= n) return;
    float di = dinv[r], d2 = di * di;
    ushort4 hu = *(const ushort4*)&Hb[(size_t)r * 128 + lane * 4];
    float4 bv  = *(const float4*)&B[lane * 4];
    float4 a0 = make_float4(fmaf(bf2f(hu.x), d2, bv.x), fmaf(bf2f(hu.y), d2, bv.y),
                            fmaf(bf2f(hu.z), d2, bv.z), fmaf(bf2f(hu.w), d2, bv.w));
    float4 a1 = make_float4(0.f, 0.f, 0.f, 0.f);
    float4 a2 = a1, a3 = a1;
    int j  = rowstart[r];
    int j1 = rowstart[r + 1];
    for (; j + 4 <= j1; j += 4) {
        int2 p0 = epair[j], p1 = epair[j + 1], p2 = epair[j + 2], p3 = epair[j + 3];
        ushort4 u0 = *(const ushort4*)&Hb[(size_t)p0.x * 128 + lane * 4];
        ushort4 u1 = *(const ushort4*)&Hb[(size_t)p1.x * 128 + lane * 4];
        ushort4 u2 = *(const ushort4*)&Hb[(size_t)p2.x * 128 + lane * 4];
        ushort4 u3 = *(const ushort4*)&Hb[(size_t)p3.x * 128 + lane * 4];
        float w0 = __int_as_float(p0.y), w1 = __int_as_float(p1.y);
        float w2 = __int_as_float(p2.y), w3 = __int_as_float(p3.y);
        a0.x = fmaf(bf2f(u0.x), w0, a0.x); a0.y = fmaf(bf2f(u0.y), w0, a0.y);
        a0.z = fmaf(bf2f(u0.z), w0, a0.z); a0.w = fmaf(bf2f(u0.w), w0, a0.w);
        a1.x = fmaf(bf2f(u1.x), w1, a1.x); a1.y = fmaf(bf2f(u1.y), w1, a1.y);
        a1.z = fmaf(bf2f(u1.z), w1, a1.z); a1.w = fmaf(bf2f(u1.w), w1, a1.w);
        a2.x = fmaf(bf2f(u2.x), w2, a2.x); a2.y = fmaf(bf2f(u2.y), w2, a2.y);
        a2.z = fmaf(bf2f(u2.z), w2, a2.z); a2.w = fmaf(bf2f(u2.w), w2, a2.w);
        a3.x = fmaf(bf2f(u3.x), w3, a3.x); a3.y = fmaf(bf2f(u3.y), w3, a3.y);
        a3.z = fmaf(bf2f(u3.z), w3, a3.z); a3.w = fmaf(bf2f(u3.w), w3, a3.w);
    }
    for (; j < j1; ++j) {
        int2 p = epair[j];
        float w = __int_as_float(p.y);
        ushort4 u = *(const ushort4*)&Hb[(size_t)p.x * 128 + lane * 4];
        a0.x = fmaf(bf2f(u.x), w, a0.x); a0.y = fmaf(bf2f(u.y), w, a0.y);
        a0.z = fmaf(bf2f(u.z), w, a0.z); a0.w = fmaf(bf2f(u.w), w, a0.w);
    }
    float4 acc = make_float4(a0.x + a1.x + a2.x + a3.x,
                             a0.y + a1.y + a2.y + a3.y,
                             a0.z + a1.z + a2.z + a3.z,
                             a0.w + a1.w + a2.w + a3.w);
    acc.x = fmaxf(acc.x, 0.f);  acc.y = fmaxf(acc.y, 0.f);
    acc.z = fmaxf(acc.z, 0.f);  acc.w = fmaxf(acc.w, 0.f);
    *(float4*)&AGG[(size_t)r * 128 + lane * 4] = acc;
}

// GEMM2: AGG[n,128] fp32 @ [128,40] -> H3 bf16
__global__ __launch_bounds__(256) void k_gemm2(
    const float* __restrict__ X, const float* __restrict__ W,
    unsigned short* __restrict__ H3b, int n)
{
    __shared__ float xs[128][17];
    __shared__ float ws[128 * 40];
    const int t  = threadIdx.x;
    const int tx = t & 7;
    const int ty = t >> 3;
    const int r0 = blockIdx.x * 128;

#pragma unroll
    for (int i = 0; i < 20; ++i) ws[t + i * 256] = W[t + i * 256];

    float acc[4][5] = {};
    for (int kc = 0; kc < 128; kc += 16) {
#pragma unroll
        for (int i = 0; i < 2; ++i) {
            int idx = t + i * 256;
            int row = idx >> 2;
            int q   = idx & 3;
            int r   = r0 + row;
            float4 v = make_float4(0.f, 0.f, 0.f, 0.f);
            if (r < n) v = *(const float4*)&X[(size_t)r * 128 + kc + q * 4];
            float* p = &xs[row][q * 4];
            p[0] = v.x; p[1] = v.y; p[2] = v.z; p[3] = v.w;
        }
        __syncthreads();
#pragma unroll
        for (int kk = 0; kk < 16; ++kk) {
            float wv[5];
            const float* wp = &ws[(kc + kk) * 40 + tx * 5];
#pragma unroll
            for (int j = 0; j < 5; ++j) wv[j] = wp[j];
#pragma unroll
            for (int i = 0; i < 4; ++i) {
                float xv = xs[ty * 4 + i][kk];
#pragma unroll
                for (int j = 0; j < 5; ++j) acc[i][j] = fmaf(xv, wv[j], acc[i][j]);
            }
        }
        __syncthreads();
    }

#pragma unroll
    for (int i = 0; i < 4; ++i) {
        int r = r0 + ty * 4 + i;
        if (r < n) {
#pragma unroll
            for (int j = 0; j < 5; ++j)
                H3b[(size_t)r * 40 + tx * 5 + j] = f2bf(acc[i][j]);
        }
    }
}

// layer-2 aggregation: 10 lanes/row (4 ch each), 320-thread blocks, 4-way unrolled
__global__ __launch_bounds__(320) void k_agg2(
    const int* __restrict__ rowstart, const int2* __restrict__ epair,
    const unsigned short* __restrict__ H3b, const float* __restrict__ B,
    const float* __restrict__ dinv, float* __restrict__ OUT, int n)
{
    int t = threadIdx.x;
    int r = blockIdx.x * 32 + t / 10;
    int q = t % 10;
    if (r >= n) return;
    float di = dinv[r], d2 = di * di;
    ushort4 hu = *(const ushort4*)&H3b[(size_t)r * 40 + q * 4];
    float4 bv  = *(const float4*)&B[q * 4];
    float4 a0 = make_float4(fmaf(bf2f(hu.x), d2, bv.x), fmaf(bf2f(hu.y), d2, bv.y),
                            fmaf(bf2f(hu.z), d2, bv.z), fmaf(bf2f(hu.w), d2, bv.w));
    float4 a1 = make_float4(0.f, 0.f, 0.f, 0.f);
    float4 a2 = a1, a3 = a1;
    int j  = rowstart[r];
    int j1 = rowstart[r + 1];
    for (; j + 4 <= j1; j += 4) {
        int2 p0 = epair[j], p1 = epair[j + 1], p2 = epair[j + 2], p3 = epair[j + 3];
        ushort4 u0 = *(const ushort4*)&H3b[(size_t)p0.x * 40 + q * 4];
        ushort4 u1 = *(const ushort4*)&H3b[(size_t)p1.x * 40 + q * 4];
        ushort4 u2 = *(const ushort4*)&H3b[(size_t)p2.x * 40 + q * 4];
        ushort4 u3 = *(const ushort4*)&H3b[(size_t)p3.x * 40 + q * 4];
        float w0 = __int_as_float(p0.y), w1 = __int_as_float(p1.y);
        float w2 = __int_as_float(p2.y), w3 = __int_as_float(p3.y);
        a0.x = fmaf(bf2f(u0.x), w0, a0.x); a0.y = fmaf(bf2f(u0.y), w0, a0.y);
        a0.z = fmaf(bf2f(u0.z), w0, a0.z); a0.w = fmaf(bf2f(u0.w), w0, a0.w);
        a1.x = fmaf(bf2f(u1.x), w1, a1.x); a1.y = fmaf(bf2f(u1.y), w1, a1.y);
        a1.z = fmaf(bf2f(u1.z), w1, a1.z); a1.w = fmaf(bf2f(u1.w), w1, a1.w);
        a2.x = fmaf(bf2f(u2.x), w2, a2.x); a2.y = fmaf(bf2f(u2.y), w2, a2.y);
        a2.z = fmaf(bf2f(u2.z), w2, a2.z); a2.w = fmaf(bf2f(u2.w), w2, a2.w);
        a3.x = fmaf(bf2f(u3.x), w3, a3.x); a3.y = fmaf(bf2f(u3.y), w3, a3.y);
        a3.z = fmaf(bf2f(u3.z), w3, a3.z); a3.w = fmaf(bf2f(u3.w), w3, a3.w);
    }
    for (; j < j1; ++j) {
        int2 p = epair[j];
        float w = __int_as_float(p.y);
        ushort4 u = *(const ushort4*)&H3b[(size_t)p.x * 40 + q * 4];
        a0.x = fmaf(bf2f(u.x), w, a0.x); a0.y = fmaf(bf2f(u.y), w, a0.y);
        a0.z = fmaf(bf2f(u.z), w, a0.z); a0.w = fmaf(bf2f(u.w), w, a0.w);
    }
    float4 acc = make_float4(a0.x + a1.x + a2.x + a3.x,
                             a0.y + a1.y + a2.y + a3.y,
                             a0.z + a1.z + a2.z + a3.z,
                             a0.w + a1.w + a2.w + a3.w);
    *(float4*)&OUT[(size_t)r * 40 + q * 4] = acc;
}

extern "C" void kernel_launch(void* const* d_in, const int* in_sizes, int n_in,
                              void* d_out, int out_size, void* d_ws, size_t ws_size,
                              hipStream_t stream) {
    const float* x  = (const float*)d_in[0];
    const int*   ei = (const int*)d_in[1];
    const float* W1 = (const float*)d_in[2];
    const float* b1 = (const float*)d_in[3];
    const float* W2 = (const float*)d_in[4];
    const float* b2 = (const float*)d_in[5];
    float* out = (float*)d_out;

    const int n = in_sizes[0] / 128;     // 50000
    const int m = in_sizes[1] / 2;       // 600000
    const int* src = ei;
    const int* dst = ei + m;
    const int nb = (n + 255) / 256;

    char* p = (char*)d_ws;
    auto take = [&](size_t bytes) { char* q = p; p += (bytes + 255) & ~(size_t)255; return q; };
    int*   cnt      = (int*)take(sizeof(int) * n);
    int*   rowstart = (int*)take(sizeof(int) * (n + 1));
    int*   cursor   = (int*)take(sizeof(int) * n);
    int*   bsum     = (int*)take(sizeof(int) * 256);
    int*   boff     = (int*)take(sizeof(int) * 256);
    int2*  epair    = (int2*)take(sizeof(int2) * m);
    float* dinv     = (float*)take(sizeof(float) * n);
    unsigned short* H1b = (unsigned short*)take(sizeof(short) * (size_t)n * 128);
    float* AGG      = (float*)take(sizeof(float) * (size_t)n * 128);
    unsigned short* H3b = H1b;           // alias: H1b dead after k_agg1

    hipMemsetAsync(cnt, 0, sizeof(int) * n, stream);
    k_hist      <<<(m + 255) / 256, 256, 0, stream>>>(dst, cnt, m);
    k_scan_local<<<nb, 256, 0, stream>>>(cnt, rowstart, bsum, dinv, n);
    k_scan_bsum <<<1, 256, 0, stream>>>(bsum, boff, nb);
    k_scan_add  <<<nb, 256, 0, stream>>>(rowstart, boff, cursor, n, m);
    k_scatter   <<<(m + 255) / 256, 256, 0, stream>>>(src, dst, dinv, cursor, epair, m);

    k_gemm1<<<(n + 127) / 128, 256, 0, stream>>>(x, W1, H1b, n);
    k_agg1 <<<(n + 7) / 8, 256, 0, stream>>>(rowstart, epair, H1b, b1, dinv, AGG, n);
    k_gemm2<<<(n + 127) / 128, 256, 0, stream>>>(AGG, W2, H3b, n);
    k_agg2 <<<(n + 31) / 32, 320, 0, stream>>>(rowstart, epair, H3b, b2, dinv, out, n);
}

// Round 6
// 167.349 us; speedup vs baseline: 8.8965x; 1.0108x over previous
//
#include <hip/hip_runtime.h>

// ---------------------------------------------------------------------------
// GCN 2-layer forward, CSR-gather formulation, bf16 gather tables.
//   CSR build: zero -> hist -> scan -> scatter (src,norm) int2 pairs by dst.
//   H1b = bf16(x@W1)                           [n,128] ushort
//   AGG = relu(b1 + H1b*dinv^2 + gather(H1b))  fp32 [n,128]
//   H3b = bf16(AGG@W2)                         [n,40] ushort
//   OUT = b2 + H3b*dinv^2 + gather(H3b)        fp32
// Gathers are 16B (uint4 = 8 bf16) per lane: 16 lanes/row (L1), 5 lanes/row (L2).
// ---------------------------------------------------------------------------

__device__ inline unsigned short f2bf(float x) {
    unsigned u = __float_as_uint(x);
    unsigned r = (u + 0x7FFFu + ((u >> 16) & 1u)) >> 16;   // round-nearest-even
    return (unsigned short)r;
}
__device__ inline float bflo(unsigned u) { return __uint_as_float(u << 16); }
__device__ inline float bfhi(unsigned u) { return __uint_as_float(u & 0xFFFF0000u); }

// unpack uint4 (8 bf16) and fma into acc[8]
__device__ inline void fma8(float* acc, uint4 uv, float wt) {
    acc[0] = fmaf(bflo(uv.x), wt, acc[0]);
    acc[1] = fmaf(bfhi(uv.x), wt, acc[1]);
    acc[2] = fmaf(bflo(uv.y), wt, acc[2]);
    acc[3] = fmaf(bfhi(uv.y), wt, acc[3]);
    acc[4] = fmaf(bflo(uv.z), wt, acc[4]);
    acc[5] = fmaf(bfhi(uv.z), wt, acc[5]);
    acc[6] = fmaf(bflo(uv.w), wt, acc[6]);
    acc[7] = fmaf(bfhi(uv.w), wt, acc[7]);
}

__global__ __launch_bounds__(256) void k_zero(int* __restrict__ cnt, int n) {
    int i = blockIdx.x * 256 + threadIdx.x;
    if (i < n) cnt[i] = 0;
}

__global__ __launch_bounds__(256) void k_hist(const int* __restrict__ dst,
                                              int* __restrict__ cnt, int m) {
    int i = blockIdx.x * 256 + threadIdx.x;
    if (i < m) atomicAdd(&cnt[dst[i]], 1);
}

__global__ __launch_bounds__(256) void k_scan_local(const int* __restrict__ cnt,
                                                    int* __restrict__ rowstart,
                                                    int* __restrict__ bsum,
                                                    float* __restrict__ dinv, int n) {
    __shared__ int s[256];
    int t = threadIdx.x;
    int i = blockIdx.x * 256 + t;
    int v = (i < n) ? cnt[i] : 0;
    if (i < n) dinv[i] = rsqrtf((float)v + 1.0f);
    s[t] = v;
    __syncthreads();
#pragma unroll
    for (int off = 1; off < 256; off <<= 1) {
        int x = s[t];
        if (t >= off) x += s[t - off];
        __syncthreads();
        s[t] = x;
        __syncthreads();
    }
    if (i < n) rowstart[i] = s[t] - v;
    if (t == 255) bsum[blockIdx.x] = s[255];
}

__global__ __launch_bounds__(256) void k_scan_bsum(int* __restrict__ bsum,
                                                   int* __restrict__ boff, int nb) {
    __shared__ int s[256];
    int t = threadIdx.x;
    int v = (t < nb) ? bsum[t] : 0;
    s[t] = v;
    __syncthreads();
#pragma unroll
    for (int off = 1; off < 256; off <<= 1) {
        int x = s[t];
        if (t >= off) x += s[t - off];
        __syncthreads();
        s[t] = x;
        __syncthreads();
    }
    if (t < nb) boff[t] = s[t] - v;
}

__global__ __launch_bounds__(256) void k_scan_add(int* __restrict__ rowstart,
                                                  const int* __restrict__ boff,
                                                  int* __restrict__ cursor, int n, int m) {
    int i = blockIdx.x * 256 + threadIdx.x;
    if (i < n) {
        int v = rowstart[i] + boff[blockIdx.x];
        rowstart[i] = v;
        cursor[i]   = v;
    }
    if (i == 0) rowstart[n] = m;
}

__global__ __launch_bounds__(256) void k_scatter(const int* __restrict__ src,
                                                 const int* __restrict__ dst,
                                                 const float* __restrict__ dinv,
                                                 int* __restrict__ cursor,
                                                 int2* __restrict__ epair, int m) {
    int e = blockIdx.x * 256 + threadIdx.x;
    if (e >= m) return;
    int s = src[e], d = dst[e];
    int pos = atomicAdd(&cursor[d], 1);
    epair[pos] = make_int2(s, __float_as_int(dinv[s] * dinv[d]));
}

// GEMM1: [n,128] @ [128,128] fp32; 128x128 tile, 8x8 micro-tile; bf16 output.
__global__ __launch_bounds__(256) void k_gemm1(
    const float* __restrict__ X, const float* __restrict__ W,
    unsigned short* __restrict__ Hb, int n)
{
    __shared__ float xs[128][36];
    __shared__ float ws[32][128];
    const int t  = threadIdx.x;
    const int tx = t & 15;
    const int ty = t >> 4;
    const int r0 = blockIdx.x * 128;
    float acc[8][8] = {};

    for (int kc = 0; kc < 128; kc += 32) {
#pragma unroll
        for (int i = 0; i < 4; ++i) {
            int idx = t + i * 256;
            int row = idx >> 3;
            int q   = idx & 7;
            int r   = r0 + row;
            float4 v = make_float4(0.f, 0.f, 0.f, 0.f);
            if (r < n) v = *(const float4*)&X[(size_t)r * 128 + kc + q * 4];
            *(float4*)&xs[row][q * 4] = v;
        }
#pragma unroll
        for (int i = 0; i < 4; ++i) {
            int idx = t + i * 256;
            int kk  = idx >> 5;
            int cg  = idx & 31;
            *(float4*)&ws[kk][cg * 4] = *(const float4*)&W[(size_t)(kc + kk) * 128 + cg * 4];
        }
        __syncthreads();
#pragma unroll
        for (int kk = 0; kk < 32; ++kk) {
            float xv[8];
#pragma unroll
            for (int i = 0; i < 8; ++i) xv[i] = xs[ty + 16 * i][kk];
            float4 w0 = *(const float4*)&ws[kk][tx * 8];
            float4 w1 = *(const float4*)&ws[kk][tx * 8 + 4];
#pragma unroll
            for (int i = 0; i < 8; ++i) {
                acc[i][0] = fmaf(xv[i], w0.x, acc[i][0]);
                acc[i][1] = fmaf(xv[i], w0.y, acc[i][1]);
                acc[i][2] = fmaf(xv[i], w0.z, acc[i][2]);
                acc[i][3] = fmaf(xv[i], w0.w, acc[i][3]);
                acc[i][4] = fmaf(xv[i], w1.x, acc[i][4]);
                acc[i][5] = fmaf(xv[i], w1.y, acc[i][5]);
                acc[i][6] = fmaf(xv[i], w1.z, acc[i][6]);
                acc[i][7] = fmaf(xv[i], w1.w, acc[i][7]);
            }
        }
        __syncthreads();
    }

#pragma unroll
    for (int i = 0; i < 8; ++i) {
        int r = r0 + ty + 16 * i;
        if (r < n) {
            ushort4 o0 = make_ushort4(f2bf(acc[i][0]), f2bf(acc[i][1]),
                                      f2bf(acc[i][2]), f2bf(acc[i][3]));
            ushort4 o1 = make_ushort4(f2bf(acc[i][4]), f2bf(acc[i][5]),
                                      f2bf(acc[i][6]), f2bf(acc[i][7]));
            *(ushort4*)&Hb[(size_t)r * 128 + tx * 8]     = o0;
            *(ushort4*)&Hb[(size_t)r * 128 + tx * 8 + 4] = o1;
        }
    }
}

// layer-1 aggregation: 16 lanes/row, 8 ch each (uint4 = 16B), 4-way unrolled, ReLU
__global__ __launch_bounds__(256) void k_agg1(
    const int* __restrict__ rowstart, const int2* __restrict__ epair,
    const unsigned short* __restrict__ Hb, const float* __restrict__ B,
    const float* __restrict__ dinv, float* __restrict__ AGG, int n)
{
    int t = threadIdx.x;
    int lane = t & 15;
    int r = blockIdx.x * 16 + (t >> 4);
    if (r >= n) return;
    float di = dinv[r], d2 = di * di;
    uint4 hu = *(const uint4*)&Hb[(size_t)r * 128 + lane * 8];
    float a0[8], a1[8] = {}, a2[8] = {}, a3[8] = {};
    {
        const float* bp = &B[lane * 8];
        float h[8] = {bflo(hu.x), bfhi(hu.x), bflo(hu.y), bfhi(hu.y),
                      bflo(hu.z), bfhi(hu.z), bflo(hu.w), bfhi(hu.w)};
#pragma unroll
        for (int c = 0; c < 8; ++c) a0[c] = fmaf(h[c], d2, bp[c]);
    }
    int j  = rowstart[r];
    int j1 = rowstart[r + 1];
    for (; j + 4 <= j1; j += 4) {
        int2 p0 = epair[j], p1 = epair[j + 1], p2 = epair[j + 2], p3 = epair[j + 3];
        uint4 u0 = *(const uint4*)&Hb[(size_t)p0.x * 128 + lane * 8];
        uint4 u1 = *(const uint4*)&Hb[(size_t)p1.x * 128 + lane * 8];
        uint4 u2 = *(const uint4*)&Hb[(size_t)p2.x * 128 + lane * 8];
        uint4 u3 = *(const uint4*)&Hb[(size_t)p3.x * 128 + lane * 8];
        fma8(a0, u0, __int_as_float(p0.y));
        fma8(a1, u1, __int_as_float(p1.y));
        fma8(a2, u2, __int_as_float(p2.y));
        fma8(a3, u3, __int_as_float(p3.y));
    }
    for (; j < j1; ++j) {
        int2 pe = epair[j];
        uint4 u = *(const uint4*)&Hb[(size_t)pe.x * 128 + lane * 8];
        fma8(a0, u, __int_as_float(pe.y));
    }
    float o[8];
#pragma unroll
    for (int c = 0; c < 8; ++c)
        o[c] = fmaxf(a0[c] + a1[c] + a2[c] + a3[c], 0.f);     // fused ReLU
    float* p = &AGG[(size_t)r * 128 + lane * 8];
    *(float4*)(p)     = make_float4(o[0], o[1], o[2], o[3]);
    *(float4*)(p + 4) = make_float4(o[4], o[5], o[6], o[7]);
}

// GEMM2: AGG[n,128] fp32 @ [128,40] -> H3 bf16
__global__ __launch_bounds__(256) void k_gemm2(
    const float* __restrict__ X, const float* __restrict__ W,
    unsigned short* __restrict__ H3b, int n)
{
    __shared__ float xs[128][17];
    __shared__ float ws[128 * 40];
    const int t  = threadIdx.x;
    const int tx = t & 7;
    const int ty = t >> 3;
    const int r0 = blockIdx.x * 128;

#pragma unroll
    for (int i = 0; i < 20; ++i) ws[t + i * 256] = W[t + i * 256];

    float acc[4][5] = {};
    for (int kc = 0; kc < 128; kc += 16) {
#pragma unroll
        for (int i = 0; i < 2; ++i) {
            int idx = t + i * 256;
            int row = idx >> 2;
            int q   = idx & 3;
            int r   = r0 + row;
            float4 v = make_float4(0.f, 0.f, 0.f, 0.f);
            if (r < n) v = *(const float4*)&X[(size_t)r * 128 + kc + q * 4];
            float* p = &xs[row][q * 4];
            p[0] = v.x; p[1] = v.y; p[2] = v.z; p[3] = v.w;
        }
        __syncthreads();
#pragma unroll
        for (int kk = 0; kk < 16; ++kk) {
            float wv[5];
            const float* wp = &ws[(kc + kk) * 40 + tx * 5];
#pragma unroll
            for (int j = 0; j < 5; ++j) wv[j] = wp[j];
#pragma unroll
            for (int i = 0; i < 4; ++i) {
                float xv = xs[ty * 4 + i][kk];
#pragma unroll
                for (int j = 0; j < 5; ++j) acc[i][j] = fmaf(xv, wv[j], acc[i][j]);
            }
        }
        __syncthreads();
    }

#pragma unroll
    for (int i = 0; i < 4; ++i) {
        int r = r0 + ty * 4 + i;
        if (r < n) {
#pragma unroll
            for (int j = 0; j < 5; ++j)
                H3b[(size_t)r * 40 + tx * 5 + j] = f2bf(acc[i][j]);
        }
    }
}

// layer-2 aggregation: 5 lanes/row, 8 ch each (uint4 = 16B), 320-thread blocks
__global__ __launch_bounds__(320) void k_agg2(
    const int* __restrict__ rowstart, const int2* __restrict__ epair,
    const unsigned short* __restrict__ H3b, const float* __restrict__ B,
    const float* __restrict__ dinv, float* __restrict__ OUT, int n)
{
    int t = threadIdx.x;
    int r = blockIdx.x * 64 + t / 5;
    int q = t % 5;
    if (r >= n) return;
    float di = dinv[r], d2 = di * di;
    uint4 hu = *(const uint4*)&H3b[(size_t)r * 40 + q * 8];
    float a0[8], a1[8] = {}, a2[8] = {}, a3[8] = {};
    {
        const float* bp = &B[q * 8];
        float h[8] = {bflo(hu.x), bfhi(hu.x), bflo(hu.y), bfhi(hu.y),
                      bflo(hu.z), bfhi(hu.z), bflo(hu.w), bfhi(hu.w)};
#pragma unroll
        for (int c = 0; c < 8; ++c) a0[c] = fmaf(h[c], d2, bp[c]);
    }
    int j  = rowstart[r];
    int j1 = rowstart[r + 1];
    for (; j + 4 <= j1; j += 4) {
        int2 p0 = epair[j], p1 = epair[j + 1], p2 = epair[j + 2], p3 = epair[j + 3];
        uint4 u0 = *(const uint4*)&H3b[(size_t)p0.x * 40 + q * 8];
        uint4 u1 = *(const uint4*)&H3b[(size_t)p1.x * 40 + q * 8];
        uint4 u2 = *(const uint4*)&H3b[(size_t)p2.x * 40 + q * 8];
        uint4 u3 = *(const uint4*)&H3b[(size_t)p3.x * 40 + q * 8];
        fma8(a0, u0, __int_as_float(p0.y));
        fma8(a1, u1, __int_as_float(p1.y));
        fma8(a2, u2, __int_as_float(p2.y));
        fma8(a3, u3, __int_as_float(p3.y));
    }
    for (; j < j1; ++j) {
        int2 pe = epair[j];
        uint4 u = *(const uint4*)&H3b[(size_t)pe.x * 40 + q * 8];
        fma8(a0, u, __int_as_float(pe.y));
    }
    float o[8];
#pragma unroll
    for (int c = 0; c < 8; ++c) o[c] = a0[c] + a1[c] + a2[c] + a3[c];
    float* p = &OUT[(size_t)r * 40 + q * 8];
    *(float4*)(p)     = make_float4(o[0], o[1], o[2], o[3]);
    *(float4*)(p + 4) = make_float4(o[4], o[5], o[6], o[7]);
}

extern "C" void kernel_launch(void* const* d_in, const int* in_sizes, int n_in,
                              void* d_out, int out_size, void* d_ws, size_t ws_size,
                              hipStream_t stream) {
    const float* x  = (const float*)d_in[0];
    const int*   ei = (const int*)d_in[1];
    const float* W1 = (const float*)d_in[2];
    const float* b1 = (const float*)d_in[3];
    const float* W2 = (const float*)d_in[4];
    const float* b2 = (const float*)d_in[5];
    float* out = (float*)d_out;

    const int n = in_sizes[0] / 128;     // 50000
    const int m = in_sizes[1] / 2;       // 600000
    const int* src = ei;
    const int* dst = ei + m;
    const int nb = (n + 255) / 256;

    char* p = (char*)d_ws;
    auto take = [&](size_t bytes) { char* q = p; p += (bytes + 255) & ~(size_t)255; return q; };
    int*   cnt      = (int*)take(sizeof(int) * n);
    int*   rowstart = (int*)take(sizeof(int) * (n + 1));
    int*   cursor   = (int*)take(sizeof(int) * n);
    int*   bsum     = (int*)take(sizeof(int) * 256);
    int*   boff     = (int*)take(sizeof(int) * 256);
    int2*  epair    = (int2*)take(sizeof(int2) * m);
    float* dinv     = (float*)take(sizeof(float) * n);
    unsigned short* H1b = (unsigned short*)take(sizeof(short) * (size_t)n * 128);
    float* AGG      = (float*)take(sizeof(float) * (size_t)n * 128);
    unsigned short* H3b = H1b;           // alias: H1b dead after k_agg1

    k_zero      <<<nb, 256, 0, stream>>>(cnt, n);
    k_hist      <<<(m + 255) / 256, 256, 0, stream>>>(dst, cnt, m);
    k_scan_local<<<nb, 256, 0, stream>>>(cnt, rowstart, bsum, dinv, n);
    k_scan_bsum <<<1, 256, 0, stream>>>(bsum, boff, nb);
    k_scan_add  <<<nb, 256, 0, stream>>>(rowstart, boff, cursor, n, m);
    k_scatter   <<<(m + 255) / 256, 256, 0, stream>>>(src, dst, dinv, cursor, epair, m);

    k_gemm1<<<(n + 127) / 128, 256, 0, stream>>>(x, W1, H1b, n);
    k_agg1 <<<(n + 15) / 16, 256, 0, stream>>>(rowstart, epair, H1b, b1, dinv, AGG, n);
    k_gemm2<<<(n + 127) / 128, 256, 0, stream>>>(AGG, W2, H3b, n);
    k_agg2 <<<(n + 63) / 64, 320, 0, stream>>>(rowstart, epair, H3b, b2, dinv, out, n);
}